// Round 5
// baseline (467.170 us; speedup 1.0000x reference)
//
#include <hip/hip_runtime.h>
#include <math.h>

#define B_  8192
#define F_  256
#define T_  32      // !! (B,F,T,C) = (8192,256,32,100) — T=32, NOT 100
#define NI_ 63
#define NL_ 64
#define C_  100
#define NG  16      // tree groups of 2 -> 512 blocks -> 2 waves/SIMD

typedef unsigned short u16;

__device__ __forceinline__ float bf2f(u16 u) {
    return __uint_as_float(((unsigned int)u) << 16);
}
__device__ __forceinline__ u16 f2bf(float f) {
    unsigned int u = __float_as_uint(f);
    u += 0x7fffu + ((u >> 16) & 1u);      // RNE
    return (u16)(u >> 16);
}
// bf16 N(0,1) -> sum|.| over 128 ~ 1e2; fp32 misread as bf16 -> huge/NaN
__device__ __forceinline__ bool detect_bf(const void* xg) {
    float det = 0.f;
    #pragma unroll
    for (int i = 0; i < 128; ++i) det += fabsf(bf2f(((const u16*)xg)[i]));
    return det < 1.0e5f;
}
__device__ __forceinline__ float ld(const void* p, int idx, bool isbf) {
    return isbf ? bf2f(((const u16*)p)[idx]) : ((const float*)p)[idx];
}

// ws layout (float units):
//   lcp   : fp32 [T_][NL_][C_]  =   204,800 f
//   part2 : fp32 [C_][B_]       =   819,200 f
//   xT    : u16  [F_][B_]       = 1,048,576 f-units
//   wT    : fp32 [T_][F_][64]   =   524,288 f   (n 63->64, pad 0)
#define WS_LCP   0
#define WS_PART  (WS_LCP + T_*NL_*C_)
#define WS_XT    (WS_PART + C_*B_)
#define WS_WT    (WS_XT + (F_*B_)/2)
#define WS_TOTAL ((size_t)WS_WT + (size_t)T_*F_*64)   // 2,596,864 f = 10.4 MiB

__global__ void k_zero(float* __restrict__ p) {
    p[blockIdx.x * 256 + threadIdx.x] = 0.f;
}

__global__ void k_zf(u16* __restrict__ out, int n) {
    int i = blockIdx.x * 256 + threadIdx.x;
    if (i < n) out[i] = 0;
}

// ---- x[b][f] -> bf16 xT[f][b] ----
__global__ void k_tx(const void* __restrict__ x, u16* __restrict__ xT) {
    __shared__ u16 tile[64][65];
    bool isbf = detect_bf(x);
    int b0 = blockIdx.x * 64, k0 = blockIdx.y * 64;
    int lr = threadIdx.x >> 6, lc = threadIdx.x & 63;
    #pragma unroll
    for (int rr = 0; rr < 16; ++rr) {
        int r = rr * 4 + lr;
        tile[r][lc] = f2bf(ld(x, (b0 + r) * F_ + (k0 + lc), isbf));
    }
    __syncthreads();
    #pragma unroll
    for (int rr = 0; rr < 16; ++rr) {
        int r = rr * 4 + lr;
        xT[(size_t)(k0 + r) * B_ + (b0 + lc)] = tile[lc][r];
    }
}

// ---- sw[t][n][k] -> fp32 wT[t][k][n64] ----
__global__ void k_tw(const void* __restrict__ sw, float* __restrict__ wT) {
    __shared__ float tile[64][65];
    bool isbf = detect_bf(sw);
    int t = blockIdx.x, k0 = blockIdx.y * 64;
    int lr = threadIdx.x >> 6, lc = threadIdx.x & 63;
    #pragma unroll
    for (int rr = 0; rr < 16; ++rr) {
        int n = rr * 4 + lr;
        float v = 0.f;
        if (n < NI_) v = ld(sw, ((size_t)t * NI_ + n) * F_ + (k0 + lc), isbf);
        tile[n][lc] = v;
    }
    __syncthreads();
    #pragma unroll
    for (int rr = 0; rr < 16; ++rr) {
        int kk = rr * 4 + lr;
        wT[(size_t)t * (F_ * 64) + (k0 + kk) * 64 + lc] = tile[lc][kk];
    }
}

// ---- weighted leaf class probs ----
__global__ void k_lcp(const void* __restrict__ ll, const void* __restrict__ tw,
                      const void* __restrict__ logT, float* __restrict__ lcp) {
    int idx = blockIdx.x * 256 + threadIdx.x;   // T_*NL_ = 2048
    if (idx >= T_ * NL_) return;
    bool isbf = detect_bf(ll);
    int t = idx >> 6;
    float temp = __expf(ld(logT, 0, isbf));
    temp = fminf(fmaxf(temp, 0.1f), 5.0f);
    float invt = 1.0f / temp;

    float m = -1e30f;
    for (int j = 0; j < T_; ++j) m = fmaxf(m, ld(tw, j, isbf));
    float s = 0.f;
    for (int j = 0; j < T_; ++j) s += __expf(ld(tw, j, isbf) - m);
    float wt = __expf(ld(tw, t, isbf) - m) / s;

    int base = idx * C_;
    float m2 = -1e30f;
    for (int c = 0; c < C_; ++c) m2 = fmaxf(m2, ld(ll, base + c, isbf));
    float s2 = 0.f;
    for (int c = 0; c < C_; ++c) s2 += __expf((ld(ll, base + c, isbf) - m2) * invt);
    float sc = wt / s2;
    for (int c = 0; c < C_; ++c)
        lcp[base + c] = sc * __expf((ld(ll, base + c, isbf) - m2) * invt);
}

// ---- main: GEMM1 -> sigmoid -> leaf walk -> class accumulate ----
__global__ __launch_bounds__(256, 2)
void k_main(const u16* __restrict__ xT, const float* __restrict__ wT,
            const void* __restrict__ sb, const void* __restrict__ logT,
            const float* __restrict__ lcp, float* __restrict__ part2) {
    int tid = threadIdx.x;
    int b = blockIdx.x * 256 + tid;
    int gI = blockIdx.y;
    bool isbf = detect_bf(sb);

    float temp = __expf(ld(logT, 0, isbf));
    temp = fminf(fmaxf(temp, 0.1f), 5.0f);
    float invt = 1.0f / temp;

    float acc[C_];
    #pragma unroll
    for (int c = 0; c < C_; ++c) acc[c] = 0.f;

    for (int t = gI * 2; t < gI * 2 + 2; ++t) {
        float an[NI_];
        #pragma unroll
        for (int n = 0; n < NI_; ++n) an[n] = 0.f;
        const float* wrow = wT + (size_t)t * (F_ * 64);
        for (int k = 0; k < F_; ++k) {
            float xv = bf2f(xT[(size_t)k * B_ + b]);   // coalesced
            const float* wk = wrow + k * 64;           // wave-uniform
            #pragma unroll
            for (int n = 0; n < NI_; ++n) an[n] = fmaf(xv, wk[n], an[n]);
        }
        #pragma unroll
        for (int n = 0; n < NI_; ++n) {
            float lg = (an[n] + ld(sb, t * NI_ + n, isbf)) * invt;
            an[n] = 1.0f / (1.0f + __expf(-lg));       // reuse as g[]
        }
        const float* lrow = lcp + (size_t)t * (NL_ * C_);
        #pragma unroll
        for (int l = 0; l < NL_; ++l) {
            int node = l + NI_;
            float p = 1.0f;
            #pragma unroll
            for (int d = 0; d < 6; ++d) {
                int par = (node - 1) >> 1;             // compile-time
                float gv = an[par];
                p = (node & 1) ? (p - p * gv) : (p * gv);  // odd=left -> 1-g
                node = par;
            }
            const float* lc = lrow + l * C_;           // wave-uniform
            #pragma unroll
            for (int c = 0; c < C_; ++c) acc[c] = fmaf(p, lc[c], acc[c]);
        }
    }
    #pragma unroll
    for (int c = 0; c < C_; ++c)
        atomicAdd(&part2[c * B_ + b], acc[c]);         // coalesced over b
}

// ---- part2[c][b] -> out[b][c] ----
__global__ void k_out(const float* __restrict__ part2, void* __restrict__ outg,
                      const void* __restrict__ xg) {
    bool isbf = detect_bf(xg);
    int idx = blockIdx.x * 256 + threadIdx.x;          // C_*B_
    int c = idx >> 13, b = idx & 8191;
    float v = part2[idx];                              // coalesced read
    if (isbf) ((u16*)outg)[(size_t)b * C_ + c] = f2bf(v);
    else      ((float*)outg)[(size_t)b * C_ + c] = v;
}

// ---- zero-ws fallback: thread-per-row, all trees ----
__global__ void k_mono(const void* __restrict__ x, const void* __restrict__ sw,
                       const void* __restrict__ sb, const void* __restrict__ ll,
                       const void* __restrict__ tw, const void* __restrict__ logT,
                       void* __restrict__ outg) {
    __shared__ float slcp[NL_ * C_];
    bool isbf = detect_bf(x);
    int tid = threadIdx.x;
    int b = blockIdx.x * 256 + tid;

    float temp = __expf(ld(logT, 0, isbf));
    temp = fminf(fmaxf(temp, 0.1f), 5.0f);
    float invt = 1.0f / temp;

    float m = -1e30f;
    for (int j = 0; j < T_; ++j) m = fmaxf(m, ld(tw, j, isbf));
    float sden = 0.f;
    for (int j = 0; j < T_; ++j) sden += __expf(ld(tw, j, isbf) - m);

    float acc[C_];
    #pragma unroll
    for (int c = 0; c < C_; ++c) acc[c] = 0.f;

    for (int t = 0; t < T_; ++t) {
        __syncthreads();
        {   // 256 threads: leaf = tid&63, c-quarter = tid>>6
            int l = tid & 63, cq = tid >> 6;
            float wt = __expf(ld(tw, t, isbf) - m) / sden;
            int base = (t * NL_ + l) * C_;
            float m2 = -1e30f;
            for (int c = 0; c < C_; ++c) m2 = fmaxf(m2, ld(ll, base + c, isbf));
            float s2 = 0.f;
            for (int c = 0; c < C_; ++c) s2 += __expf((ld(ll, base + c, isbf) - m2) * invt);
            float sc = wt / s2;
            for (int c = cq * 25; c < cq * 25 + 25; ++c)
                slcp[l * C_ + c] = sc * __expf((ld(ll, base + c, isbf) - m2) * invt);
        }
        __syncthreads();

        float an[NI_];
        #pragma unroll
        for (int n = 0; n < NI_; ++n) an[n] = 0.f;
        for (int k = 0; k < F_; ++k) {
            float xv = ld(x, (size_t)b * F_ + k, isbf);
            #pragma unroll
            for (int n = 0; n < NI_; ++n)
                an[n] = fmaf(xv, ld(sw, ((size_t)t * NI_ + n) * F_ + k, isbf), an[n]);
        }
        #pragma unroll
        for (int n = 0; n < NI_; ++n) {
            float lg = (an[n] + ld(sb, t * NI_ + n, isbf)) * invt;
            an[n] = 1.0f / (1.0f + __expf(-lg));
        }
        #pragma unroll
        for (int l = 0; l < NL_; ++l) {
            int node = l + NI_;
            float p = 1.0f;
            #pragma unroll
            for (int d = 0; d < 6; ++d) {
                int par = (node - 1) >> 1;
                float gv = an[par];
                p = (node & 1) ? (p - p * gv) : (p * gv);
                node = par;
            }
            #pragma unroll
            for (int c = 0; c < C_; ++c)
                acc[c] = fmaf(p, slcp[l * C_ + c], acc[c]);
        }
    }
    for (int c = 0; c < C_; ++c) {
        if (isbf) ((u16*)outg)[(size_t)b * C_ + c] = f2bf(acc[c]);
        else      ((float*)outg)[(size_t)b * C_ + c] = acc[c];
    }
}

extern "C" void kernel_launch(void* const* d_in, const int* in_sizes, int n_in,
                              void* d_out, int out_size, void* d_ws, size_t ws_size,
                              hipStream_t stream) {
    bool ok = (n_in >= 6)
           && (in_sizes[0] == B_ * F_)          // 2,097,152
           && (in_sizes[1] == T_ * NI_ * F_)    //   516,096
           && (in_sizes[2] == T_ * NI_)         //     2,016
           && (in_sizes[3] == T_ * NL_ * C_)    //   204,800
           && (in_sizes[4] == T_)               //        32
           && (in_sizes[5] == 1)
           && (out_size == B_ * C_);            //   819,200

    if (!ok) {
        k_zf<<<(out_size + 255) / 256, 256, 0, stream>>>((u16*)d_out, out_size);
        return;
    }

    const void* x    = d_in[0];
    const void* sw   = d_in[1];
    const void* sb   = d_in[2];
    const void* ll   = d_in[3];
    const void* tw   = d_in[4];
    const void* logT = d_in[5];

    if (ws_size >= WS_TOTAL * sizeof(float)) {
        float* ws    = (float*)d_ws;
        float* lcp   = ws + WS_LCP;
        float* part2 = ws + WS_PART;
        u16*   xT    = (u16*)(ws + WS_XT);
        float* wT    = ws + WS_WT;

        k_zero<<<(C_ * B_) / 256, 256, 0, stream>>>(part2);
        k_lcp <<<(T_ * NL_ + 255) / 256, 256, 0, stream>>>(ll, tw, logT, lcp);
        k_tx  <<<dim3(B_ / 64, F_ / 64), 256, 0, stream>>>(x, xT);
        k_tw  <<<dim3(T_, F_ / 64), 256, 0, stream>>>(sw, wT);
        k_main<<<dim3(B_ / 256, NG), 256, 0, stream>>>(xT, wT, sb, logT, lcp, part2);
        k_out <<<(C_ * B_) / 256, 256, 0, stream>>>(part2, d_out, x);
    } else {
        k_mono<<<B_ / 256, 256, 0, stream>>>(x, sw, sb, ll, tw, logT, d_out);
    }
}

// Round 10
// 252.401 us; speedup vs baseline: 1.8509x; 1.8509x over previous
//
#include <hip/hip_runtime.h>
#include <math.h>

#define B_  8192
#define F_  256
#define T_  32
#define NI_ 63
#define NL_ 64
#define C_  100
#define CP_ 112            // class dim padded to 7*16
#define K2_ (T_*NL_)       // 2048 = GEMM2 K

typedef unsigned short u16;
typedef __attribute__((ext_vector_type(8))) short bf16x8;   // MFMA A/B frag
typedef __attribute__((ext_vector_type(4))) float f32x4;    // MFMA C/D frag

__device__ __forceinline__ float bf2f(u16 u) {
    return __uint_as_float(((unsigned int)u) << 16);
}
__device__ __forceinline__ u16 f2bf(float f) {
    unsigned int u = __float_as_uint(f);
    u += 0x7fffu + ((u >> 16) & 1u);      // RNE
    return (u16)(u >> 16);
}
// inputs are fp32 (R6 NaN evidence); detector kept for robustness
__device__ __forceinline__ bool detect_bf(const void* p) {
    float det = 0.f;
    #pragma unroll
    for (int i = 0; i < 128; ++i) det += fabsf(bf2f(((const u16*)p)[i]));
    return det < 1.0e5f;
}
__device__ __forceinline__ float ld(const void* p, size_t idx, bool isbf) {
    return isbf ? bf2f(((const u16*)p)[idx]) : ((const float*)p)[idx];
}
// OUTPUT IS FP32 (R5 pass via detect->fp32 store; R7-R9 bf16 stores garbled it).
// Keep the R5-proven adaptive store keyed on x's dtype.
__device__ __forceinline__ void st_out(void* outg, size_t idx, float v, bool isbf) {
    if (isbf) ((u16*)outg)[idx] = f2bf(v);
    else      ((float*)outg)[idx] = v;
}

// ws layout (bytes):
//   xb     : u16 [B_][F_]     = 4,194,304
//   swb    : u16 [T_][NI_][F_]= 1,032,192
//   lcpT   : u16 [CP_][K2_]   =   458,752
//   outacc : f32 [B_][CP_]    = 3,670,016
#define WSB_XB   0
#define WSB_SWB  (WSB_XB + B_*F_*2)
#define WSB_LCPT (WSB_SWB + T_*NI_*F_*2)
#define WSB_ACC  (WSB_LCPT + CP_*K2_*2)
#define WSB_TOT  ((size_t)WSB_ACC + (size_t)B_*CP_*4)   // 9,355,264 B ≈ 8.9 MiB (< R5-proven 10.39 MB)

__global__ void k_zf(float* __restrict__ out, int n) {   // fp32 zero-fill (guard path)
    int i = blockIdx.x * 256 + threadIdx.x;
    if (i < n) out[i] = 0.f;
}
__global__ void k_zacc(float* __restrict__ p) {
    p[blockIdx.x * 256 + threadIdx.x] = 0.f;
}
__global__ void k_cvt(const void* __restrict__ src, u16* __restrict__ dst, int n) {
    bool isbf = detect_bf(src);
    int i = blockIdx.x * 256 + threadIdx.x;
    if (i < n) dst[i] = isbf ? ((const u16*)src)[i] : f2bf(((const float*)src)[i]);
}

// ---- lcpT[c][t*64+l] = softmax(tw)[t] * softmax(ll[t,l,:]/temp)[c], bf16 ----
__global__ void k_lcpT(const void* __restrict__ ll, const void* __restrict__ tw,
                       const void* __restrict__ logT, u16* __restrict__ lcpT) {
    int idx = blockIdx.x * 256 + threadIdx.x;   // over T_*NL_ = 2048
    bool isbf = detect_bf(ll);
    int t = idx >> 6;
    float temp = __expf(ld(logT, 0, isbf));
    temp = fminf(fmaxf(temp, 0.1f), 5.0f);
    float invt = 1.0f / temp;

    float m = -1e30f;
    for (int j = 0; j < T_; ++j) m = fmaxf(m, ld(tw, j, isbf));
    float s = 0.f;
    for (int j = 0; j < T_; ++j) s += __expf(ld(tw, j, isbf) - m);
    float wt = __expf(ld(tw, t, isbf) - m) / s;

    size_t base = (size_t)idx * C_;
    float m2 = -1e30f;
    for (int c = 0; c < C_; ++c) m2 = fmaxf(m2, ld(ll, base + c, isbf));
    float s2 = 0.f;
    for (int c = 0; c < C_; ++c) s2 += __expf((ld(ll, base + c, isbf) - m2) * invt);
    float sc = wt / s2;
    for (int c = 0; c < C_; ++c)
        lcpT[(size_t)c * K2_ + idx] = f2bf(sc * __expf((ld(ll, base + c, isbf) - m2) * invt));
    for (int c = C_; c < CP_; ++c)
        lcpT[(size_t)c * K2_ + idx] = 0;        // pad rows feed discarded C-cols
}

// ---- fused: MFMA GEMM1 -> sigmoid -> subtree leaf walk -> MFMA GEMM2 ----
// grid (B_/64, 4), block 256; wave owns 16 b-rows; y-slice does 8 trees
__global__ __launch_bounds__(256, 2)
void k_fused(const u16* __restrict__ xb, const u16* __restrict__ swb,
             const float* __restrict__ sb, const float* __restrict__ logT,
             const u16* __restrict__ lcpT, float* __restrict__ outacc) {
    __shared__ float slog[4][16][65];
    int tid  = threadIdx.x;
    int w    = tid >> 6;
    int lane = tid & 63;
    int col  = lane & 15;
    int quad = lane >> 4;
    int mb   = blockIdx.x * 64 + w * 16;
    int tg   = blockIdx.y;

    float temp = __expf(logT[0]);
    temp = fminf(fmaxf(temp, 0.1f), 5.0f);
    float invt = 1.0f / temp;

    // GEMM1 A frags: A[m=col][k=ks*32+quad*8+j] from xb[b][f]
    bf16x8 afr[8];
    #pragma unroll
    for (int ks = 0; ks < 8; ++ks)
        afr[ks] = *(const bf16x8*)(xb + (size_t)(mb + col) * F_ + ks * 32 + quad * 8);

    f32x4 accO[7];
    #pragma unroll
    for (int i = 0; i < 7; ++i) accO[i] = (f32x4){0.f, 0.f, 0.f, 0.f};

    for (int ti = 0; ti < 8; ++ti) {
        int t = tg * 8 + ti;

        // ---- GEMM1: logits[16 b][64 n] over K=256
        f32x4 acc[4];
        #pragma unroll
        for (int i = 0; i < 4; ++i) acc[i] = (f32x4){0.f, 0.f, 0.f, 0.f};
        #pragma unroll
        for (int ks = 0; ks < 8; ++ks) {
            #pragma unroll
            for (int nt = 0; nt < 4; ++nt) {
                int n  = nt * 16 + col;
                int ne = n > 62 ? 62 : n;        // pad row; its column never read
                bf16x8 bfr = *(const bf16x8*)(swb + ((size_t)t * NI_ + ne) * F_
                                              + ks * 32 + quad * 8);
                acc[nt] = __builtin_amdgcn_mfma_f32_16x16x32_bf16(afr[ks], bfr, acc[nt], 0, 0, 0);
            }
        }

        __syncthreads();   // prev-iteration slog readers done
        // ---- C/D epilogue (col=lane&15, row=quad*4+r): bias+sigmoid -> slog[row][n]
        #pragma unroll
        for (int nt = 0; nt < 4; ++nt) {
            int n = nt * 16 + col;
            float bias = (n < NI_) ? sb[t * NI_ + n] : 0.f;
            #pragma unroll
            for (int r = 0; r < 4; ++r) {
                float lg = (acc[nt][r] + bias) * invt;
                slog[w][quad * 4 + r][n] = 1.0f / (1.0f + __expf(-lg));
            }
        }
        __syncthreads();

        // ---- leaf walk: lane builds its GEMM2 A-frag slots directly
        //      (subtree roots s0=7+quad -> leaves quad*8+j, s1=11+quad -> 32+quad*8+j)
        bf16x8 af0, af1;
        #pragma unroll
        for (int grp = 0; grp < 2; ++grp) {
            int s = (grp ? 11 : 7) + quad;
            float pref = 1.0f;
            int node = s;
            #pragma unroll
            for (int d = 0; d < 3; ++d) {
                int par = (node - 1) >> 1;
                float g = slog[w][col][par];
                pref = (node & 1) ? (pref - pref * g) : (pref * g);  // odd=left -> 1-g
                node = par;
            }
            float gs  = slog[w][col][s];
            float gl  = slog[w][col][2 * s + 1];
            float gr  = slog[w][col][2 * s + 2];
            float g00 = slog[w][col][4 * s + 3];
            float g01 = slog[w][col][4 * s + 4];
            float g10 = slog[w][col][4 * s + 5];
            float g11 = slog[w][col][4 * s + 6];
            #pragma unroll
            for (int j = 0; j < 8; ++j) {
                const int b2 = (j >> 2) & 1, b1 = (j >> 1) & 1, b0 = j & 1;
                float f3 = b2 ? gs : 1.0f - gs;
                float c1 = b2 ? gr : gl;
                float f4 = b1 ? c1 : 1.0f - c1;
                float c2 = b2 ? (b1 ? g11 : g10) : (b1 ? g01 : g00);
                float f5 = b0 ? c2 : 1.0f - c2;
                float p  = pref * f3 * f4 * f5;
                if (grp == 0) af0[j] = (short)f2bf(p);
                else          af1[j] = (short)f2bf(p);
            }
        }

        // ---- GEMM2: out[16 b][112 c] += leafprobs x lcpT (K=64 slice of tree t)
        #pragma unroll
        for (int nt = 0; nt < 7; ++nt) {
            int n = nt * 16 + col;
            const bf16x8 b0 = *(const bf16x8*)(lcpT + (size_t)n * K2_ + t * NL_ + quad * 8);
            const bf16x8 b1 = *(const bf16x8*)(lcpT + (size_t)n * K2_ + t * NL_ + 32 + quad * 8);
            accO[nt] = __builtin_amdgcn_mfma_f32_16x16x32_bf16(af0, b0, accO[nt], 0, 0, 0);
            accO[nt] = __builtin_amdgcn_mfma_f32_16x16x32_bf16(af1, b1, accO[nt], 0, 0, 0);
        }
    }

    // ---- fp32 atomics (4 y-slices per cell), coalesced-ish over c
    #pragma unroll
    for (int nt = 0; nt < 7; ++nt) {
        int c = nt * 16 + col;
        #pragma unroll
        for (int r = 0; r < 4; ++r) {
            int b = mb + quad * 4 + r;
            atomicAdd(&outacc[(size_t)b * CP_ + c], accO[nt][r]);
        }
    }
}

// ---- outacc[b][112] -> out[b][100], ADAPTIVE store (fp32 here) ----
__global__ void k_fin(const float* __restrict__ outacc, void* __restrict__ outg,
                      const void* __restrict__ xg) {
    bool isbf = detect_bf(xg);
    int idx = blockIdx.x * 256 + threadIdx.x;    // over B_*CP_
    int b = idx / CP_;
    int c = idx - b * CP_;
    if (c < C_) st_out(outg, (size_t)b * C_ + c, outacc[idx], isbf);
}

// ---- zero-ws fallback (R5 structure), adaptive store ----
__global__ void k_mono(const void* __restrict__ x, const void* __restrict__ sw,
                       const void* __restrict__ sb, const void* __restrict__ ll,
                       const void* __restrict__ tw, const void* __restrict__ logT,
                       void* __restrict__ outg) {
    __shared__ float slcp[NL_ * C_];
    bool isbf = detect_bf(x);
    int tid = threadIdx.x;
    int b = blockIdx.x * 256 + tid;

    float temp = __expf(ld(logT, 0, isbf));
    temp = fminf(fmaxf(temp, 0.1f), 5.0f);
    float invt = 1.0f / temp;

    float m = -1e30f;
    for (int j = 0; j < T_; ++j) m = fmaxf(m, ld(tw, j, isbf));
    float sden = 0.f;
    for (int j = 0; j < T_; ++j) sden += __expf(ld(tw, j, isbf) - m);

    float acc[C_];
    #pragma unroll
    for (int c = 0; c < C_; ++c) acc[c] = 0.f;

    for (int t = 0; t < T_; ++t) {
        __syncthreads();
        {
            int l = tid & 63, cq = tid >> 6;
            float wt = __expf(ld(tw, t, isbf) - m) / sden;
            size_t base = ((size_t)t * NL_ + l) * C_;
            float m2 = -1e30f;
            for (int c = 0; c < C_; ++c) m2 = fmaxf(m2, ld(ll, base + c, isbf));
            float s2 = 0.f;
            for (int c = 0; c < C_; ++c) s2 += __expf((ld(ll, base + c, isbf) - m2) * invt);
            float sc = wt / s2;
            for (int c = cq * 25; c < cq * 25 + 25; ++c)
                slcp[l * C_ + c] = sc * __expf((ld(ll, base + c, isbf) - m2) * invt);
        }
        __syncthreads();

        float an[NI_];
        #pragma unroll
        for (int n = 0; n < NI_; ++n) an[n] = 0.f;
        for (int k = 0; k < F_; ++k) {
            float xv = ld(x, (size_t)b * F_ + k, isbf);
            #pragma unroll
            for (int n = 0; n < NI_; ++n)
                an[n] = fmaf(xv, ld(sw, ((size_t)t * NI_ + n) * F_ + k, isbf), an[n]);
        }
        #pragma unroll
        for (int n = 0; n < NI_; ++n) {
            float lg = (an[n] + ld(sb, t * NI_ + n, isbf)) * invt;
            an[n] = 1.0f / (1.0f + __expf(-lg));
        }
        #pragma unroll
        for (int l = 0; l < NL_; ++l) {
            int node = l + NI_;
            float p = 1.0f;
            #pragma unroll
            for (int d = 0; d < 6; ++d) {
                int par = (node - 1) >> 1;
                float gv = an[par];
                p = (node & 1) ? (p - p * gv) : (p * gv);
                node = par;
            }
            #pragma unroll
            for (int c = 0; c < C_; ++c)
                acc[c] = fmaf(p, slcp[l * C_ + c], acc[c]);
        }
    }
    for (int c = 0; c < C_; ++c)
        st_out(outg, (size_t)b * C_ + c, acc[c], isbf);
}

extern "C" void kernel_launch(void* const* d_in, const int* in_sizes, int n_in,
                              void* d_out, int out_size, void* d_ws, size_t ws_size,
                              hipStream_t stream) {
    bool ok = (n_in >= 6)
           && (in_sizes[0] == B_ * F_)
           && (in_sizes[1] == T_ * NI_ * F_)
           && (in_sizes[2] == T_ * NI_)
           && (in_sizes[3] == T_ * NL_ * C_)
           && (in_sizes[4] == T_)
           && (in_sizes[5] == 1)
           && (out_size == B_ * C_);
    if (!ok) {
        k_zf<<<(out_size + 255) / 256, 256, 0, stream>>>((float*)d_out, out_size);
        return;
    }

    const void* x    = d_in[0];
    const void* sw   = d_in[1];
    const void* sb   = d_in[2];   // fp32
    const void* ll   = d_in[3];
    const void* tw   = d_in[4];
    const void* logT = d_in[5];

    if (ws_size >= WSB_TOT) {
        u16*   xb     = (u16*)((char*)d_ws + WSB_XB);
        u16*   swb    = (u16*)((char*)d_ws + WSB_SWB);
        u16*   lcpT   = (u16*)((char*)d_ws + WSB_LCPT);
        float* outacc = (float*)((char*)d_ws + WSB_ACC);

        k_cvt  <<<(B_ * F_) / 256, 256, 0, stream>>>(x, xb, B_ * F_);
        k_cvt  <<<(T_ * NI_ * F_ + 255) / 256, 256, 0, stream>>>(sw, swb, T_ * NI_ * F_);
        k_lcpT <<<(T_ * NL_) / 256, 256, 0, stream>>>(ll, tw, logT, lcpT);
        k_zacc <<<(B_ * CP_) / 256, 256, 0, stream>>>(outacc);
        k_fused<<<dim3(B_ / 64, 4), 256, 0, stream>>>(xb, swb, (const float*)sb,
                                                      (const float*)logT, lcpT, outacc);
        k_fin  <<<(B_ * CP_) / 256, 256, 0, stream>>>(outacc, d_out, x);
    } else {
        k_mono<<<B_ / 256, 256, 0, stream>>>(x, sw, sb, ll, tw, logT, d_out);
    }
}

// Round 11
// 209.524 us; speedup vs baseline: 2.2297x; 1.2046x over previous
//
#include <hip/hip_runtime.h>
#include <math.h>

#define B_  8192
#define F_  256
#define T_  32
#define NI_ 63
#define NL_ 64
#define C_  100
#define K2_ (T_*NL_)       // 2048 = GEMM2 K
#define NG  8              // y-slices (4 trees each) -> 1024 blocks -> 4 blocks/CU
#define TPG 4              // trees per y-slice

typedef unsigned short u16;
typedef __attribute__((ext_vector_type(8))) short bf16x8;   // MFMA A/B frag
typedef __attribute__((ext_vector_type(4))) float f32x4;    // MFMA C/D frag

__device__ __forceinline__ u16 f2bf(float f) {
    unsigned int u = __float_as_uint(f);
    u += 0x7fffu + ((u >> 16) & 1u);      // RNE
    return (u16)(u >> 16);
}

// ws layout (bytes):  (inputs/outputs are fp32 — established R5/R6/R10)
//   swb  : u16 [T_][NI_][F_] = 1,032,192
//   lcpT : u16 [112][K2_]    =   458,752
#define WSB_SWB  0
#define WSB_LCPT (T_*NI_*F_*2)
#define WSB_TOT  ((size_t)WSB_LCPT + 112*K2_*2)   // 1,490,944 B ≈ 1.4 MiB

// ---- prep: zero d_out + cvt sw->bf16 + weighted leaf-class-prob table ----
#define ZBLK   (B_*C_/256)        // 3200
#define SWBLK  (T_*NI_*F_/256)    // 2016
#define LCPBLK (T_*NL_/256)       // 8
__global__ void k_prep(const float* __restrict__ sw, const float* __restrict__ ll,
                       const float* __restrict__ tw, const float* __restrict__ logT,
                       u16* __restrict__ swb, u16* __restrict__ lcpT,
                       float* __restrict__ out) {
    int blk = blockIdx.x, tid = threadIdx.x;
    if (blk < ZBLK) {                       // zero output (atomic base)
        out[blk * 256 + tid] = 0.f;
        return;
    }
    blk -= ZBLK;
    if (blk < SWBLK) {                      // split_weights -> bf16
        int i = blk * 256 + tid;
        swb[i] = f2bf(sw[i]);
        return;
    }
    blk -= SWBLK;
    int idx = blk * 256 + tid;              // leaf row: t*64 + l, 0..2047
    int t = idx >> 6;
    float temp = __expf(logT[0]);
    temp = fminf(fmaxf(temp, 0.1f), 5.0f);
    float invt = 1.0f / temp;

    float m = -1e30f;
    for (int j = 0; j < T_; ++j) m = fmaxf(m, tw[j]);
    float s = 0.f;
    for (int j = 0; j < T_; ++j) s += __expf(tw[j] - m);
    float wt = __expf(tw[t] - m) / s;

    const float* row = ll + (size_t)idx * C_;
    float m2 = -1e30f;
    for (int c = 0; c < C_; ++c) m2 = fmaxf(m2, row[c]);
    float s2 = 0.f;
    for (int c = 0; c < C_; ++c) s2 += __expf((row[c] - m2) * invt);
    float sc = wt / s2;
    for (int c = 0; c < C_; ++c)
        lcpT[(size_t)c * K2_ + idx] = f2bf(sc * __expf((row[c] - m2) * invt));
    for (int c = C_; c < 112; ++c)
        lcpT[(size_t)c * K2_ + idx] = 0;    // pad rows feed discarded C-cols
}

// ---- fused: MFMA GEMM1 -> sigmoid -> subtree leaf walk -> MFMA GEMM2 ----
// grid (B_/64, NG), block 256; wave owns 16 b-rows; y-slice does TPG trees.
// Numerics identical to R10 (verified) modulo atomic-add order.
__global__ __launch_bounds__(256, 4)
void k_fused(const float* __restrict__ x, const u16* __restrict__ swb,
             const float* __restrict__ sb, const float* __restrict__ logT,
             const u16* __restrict__ lcpT, float* __restrict__ out) {
    __shared__ float slog[4][16][68];       // stride 68 (=4 mod 8): 2-way writes = free
    int tid  = threadIdx.x;
    int w    = tid >> 6;
    int lane = tid & 63;
    int col  = lane & 15;
    int quad = lane >> 4;
    int mb   = blockIdx.x * 64 + w * 16;
    int tg   = blockIdx.y;

    float temp = __expf(logT[0]);
    temp = fminf(fmaxf(temp, 0.1f), 5.0f);
    float invt = 1.0f / temp;

    // A-frags packed in-register from fp32 x (same f2bf values as R10's staging)
    bf16x8 afr[8];
    #pragma unroll
    for (int ks = 0; ks < 8; ++ks) {
        const float4* px = (const float4*)(x + (size_t)(mb + col) * F_ + ks * 32 + quad * 8);
        float4 v0 = px[0], v1 = px[1];
        bf16x8 a;
        a[0] = (short)f2bf(v0.x); a[1] = (short)f2bf(v0.y);
        a[2] = (short)f2bf(v0.z); a[3] = (short)f2bf(v0.w);
        a[4] = (short)f2bf(v1.x); a[5] = (short)f2bf(v1.y);
        a[6] = (short)f2bf(v1.z); a[7] = (short)f2bf(v1.w);
        afr[ks] = a;
    }

    f32x4 accO[7];
    #pragma unroll
    for (int i = 0; i < 7; ++i) accO[i] = (f32x4){0.f, 0.f, 0.f, 0.f};

    for (int ti = 0; ti < TPG; ++ti) {
        int t = tg * TPG + ti;

        // ---- GEMM1: logits[16 b][64 n] over K=256
        f32x4 acc[4];
        #pragma unroll
        for (int i = 0; i < 4; ++i) acc[i] = (f32x4){0.f, 0.f, 0.f, 0.f};
        #pragma unroll
        for (int ks = 0; ks < 8; ++ks) {
            #pragma unroll
            for (int nt = 0; nt < 4; ++nt) {
                int n  = nt * 16 + col;
                int ne = n > 62 ? 62 : n;        // pad row; its column never read
                bf16x8 bfr = *(const bf16x8*)(swb + ((size_t)t * NI_ + ne) * F_
                                              + ks * 32 + quad * 8);
                acc[nt] = __builtin_amdgcn_mfma_f32_16x16x32_bf16(afr[ks], bfr, acc[nt], 0, 0, 0);
            }
        }

        __syncthreads();   // prev-iteration slog readers done
        // ---- C/D epilogue (R10-verified mapping): bias+sigmoid -> slog[quad*4+r][n]
        #pragma unroll
        for (int nt = 0; nt < 4; ++nt) {
            int n = nt * 16 + col;
            float bias = (n < NI_) ? sb[t * NI_ + n] : 0.f;
            #pragma unroll
            for (int r = 0; r < 4; ++r) {
                float lg = (acc[nt][r] + bias) * invt;
                slog[w][quad * 4 + r][n] = 1.0f / (1.0f + __expf(-lg));
            }
        }
        __syncthreads();

        // ---- leaf walk (R10-verified): lane builds its GEMM2 A-frag slots
        bf16x8 af0, af1;
        #pragma unroll
        for (int grp = 0; grp < 2; ++grp) {
            int s = (grp ? 11 : 7) + quad;
            float pref = 1.0f;
            int node = s;
            #pragma unroll
            for (int d = 0; d < 3; ++d) {
                int par = (node - 1) >> 1;
                float g = slog[w][col][par];
                pref = (node & 1) ? (pref - pref * g) : (pref * g);  // odd=left -> 1-g
                node = par;
            }
            float gs  = slog[w][col][s];
            float gl  = slog[w][col][2 * s + 1];
            float gr  = slog[w][col][2 * s + 2];
            float g00 = slog[w][col][4 * s + 3];
            float g01 = slog[w][col][4 * s + 4];
            float g10 = slog[w][col][4 * s + 5];
            float g11 = slog[w][col][4 * s + 6];
            #pragma unroll
            for (int j = 0; j < 8; ++j) {
                const int b2 = (j >> 2) & 1, b1 = (j >> 1) & 1, b0 = j & 1;
                float f3 = b2 ? gs : 1.0f - gs;
                float c1 = b2 ? gr : gl;
                float f4 = b1 ? c1 : 1.0f - c1;
                float c2 = b2 ? (b1 ? g11 : g10) : (b1 ? g01 : g00);
                float f5 = b0 ? c2 : 1.0f - c2;
                float p  = pref * f3 * f4 * f5;
                if (grp == 0) af0[j] = (short)f2bf(p);
                else          af1[j] = (short)f2bf(p);
            }
        }

        // ---- GEMM2: out[16 b][112 c] += leafprobs x lcpT (K=64 slice of tree t)
        #pragma unroll
        for (int nt = 0; nt < 7; ++nt) {
            int n = nt * 16 + col;
            const bf16x8 b0 = *(const bf16x8*)(lcpT + (size_t)n * K2_ + t * NL_ + quad * 8);
            const bf16x8 b1 = *(const bf16x8*)(lcpT + (size_t)n * K2_ + t * NL_ + 32 + quad * 8);
            accO[nt] = __builtin_amdgcn_mfma_f32_16x16x32_bf16(af0, b0, accO[nt], 0, 0, 0);
            accO[nt] = __builtin_amdgcn_mfma_f32_16x16x32_bf16(af1, b1, accO[nt], 0, 0, 0);
        }
    }

    // ---- fp32 atomics straight into d_out (zeroed by k_prep); NG contributors/cell
    #pragma unroll
    for (int nt = 0; nt < 7; ++nt) {
        int c = nt * 16 + col;
        if (c < C_) {
            #pragma unroll
            for (int r = 0; r < 4; ++r) {
                int b = mb + quad * 4 + r;
                atomicAdd(&out[(size_t)b * C_ + c], accO[nt][r]);
            }
        }
    }
}

// ---- guard path: zero fp32 output ----
__global__ void k_zf(float* __restrict__ out, int n) {
    int i = blockIdx.x * 256 + threadIdx.x;
    if (i < n) out[i] = 0.f;
}

// ---- zero-ws fallback (R5-verified structure, fp32 I/O) ----
__global__ void k_mono(const float* __restrict__ x, const float* __restrict__ sw,
                       const float* __restrict__ sb, const float* __restrict__ ll,
                       const float* __restrict__ tw, const float* __restrict__ logT,
                       float* __restrict__ outg) {
    __shared__ float slcp[NL_ * C_];
    int tid = threadIdx.x;
    int b = blockIdx.x * 256 + tid;

    float temp = __expf(logT[0]);
    temp = fminf(fmaxf(temp, 0.1f), 5.0f);
    float invt = 1.0f / temp;

    float m = -1e30f;
    for (int j = 0; j < T_; ++j) m = fmaxf(m, tw[j]);
    float sden = 0.f;
    for (int j = 0; j < T_; ++j) sden += __expf(tw[j] - m);

    float acc[C_];
    #pragma unroll
    for (int c = 0; c < C_; ++c) acc[c] = 0.f;

    for (int t = 0; t < T_; ++t) {
        __syncthreads();
        {
            int l = tid & 63, cq = tid >> 6;
            float wt = __expf(tw[t] - m) / sden;
            const float* row = ll + ((size_t)t * NL_ + l) * C_;
            float m2 = -1e30f;
            for (int c = 0; c < C_; ++c) m2 = fmaxf(m2, row[c]);
            float s2 = 0.f;
            for (int c = 0; c < C_; ++c) s2 += __expf((row[c] - m2) * invt);
            float sc = wt / s2;
            for (int c = cq * 25; c < cq * 25 + 25; ++c)
                slcp[l * C_ + c] = sc * __expf((row[c] - m2) * invt);
        }
        __syncthreads();

        float an[NI_];
        #pragma unroll
        for (int n = 0; n < NI_; ++n) an[n] = 0.f;
        for (int k = 0; k < F_; ++k) {
            float xv = x[(size_t)b * F_ + k];
            #pragma unroll
            for (int n = 0; n < NI_; ++n)
                an[n] = fmaf(xv, sw[((size_t)t * NI_ + n) * F_ + k], an[n]);
        }
        #pragma unroll
        for (int n = 0; n < NI_; ++n) {
            float lg = (an[n] + sb[t * NI_ + n]) * invt;
            an[n] = 1.0f / (1.0f + __expf(-lg));
        }
        #pragma unroll
        for (int l = 0; l < NL_; ++l) {
            int node = l + NI_;
            float p = 1.0f;
            #pragma unroll
            for (int d = 0; d < 6; ++d) {
                int par = (node - 1) >> 1;
                float gv = an[par];
                p = (node & 1) ? (p - p * gv) : (p * gv);
                node = par;
            }
            #pragma unroll
            for (int c = 0; c < C_; ++c)
                acc[c] = fmaf(p, slcp[l * C_ + c], acc[c]);
        }
    }
    for (int c = 0; c < C_; ++c)
        outg[(size_t)b * C_ + c] = acc[c];
}

extern "C" void kernel_launch(void* const* d_in, const int* in_sizes, int n_in,
                              void* d_out, int out_size, void* d_ws, size_t ws_size,
                              hipStream_t stream) {
    bool ok = (n_in >= 6)
           && (in_sizes[0] == B_ * F_)
           && (in_sizes[1] == T_ * NI_ * F_)
           && (in_sizes[2] == T_ * NI_)
           && (in_sizes[3] == T_ * NL_ * C_)
           && (in_sizes[4] == T_)
           && (in_sizes[5] == 1)
           && (out_size == B_ * C_);
    if (!ok) {
        k_zf<<<(out_size + 255) / 256, 256, 0, stream>>>((float*)d_out, out_size);
        return;
    }

    const float* x    = (const float*)d_in[0];
    const float* sw   = (const float*)d_in[1];
    const float* sb   = (const float*)d_in[2];
    const float* ll   = (const float*)d_in[3];
    const float* tw   = (const float*)d_in[4];
    const float* logT = (const float*)d_in[5];
    float* out = (float*)d_out;

    if (ws_size >= WSB_TOT) {
        u16* swb  = (u16*)((char*)d_ws + WSB_SWB);
        u16* lcpT = (u16*)((char*)d_ws + WSB_LCPT);

        k_prep <<<ZBLK + SWBLK + LCPBLK, 256, 0, stream>>>(sw, ll, tw, logT, swb, lcpT, out);
        k_fused<<<dim3(B_ / 64, NG), 256, 0, stream>>>(x, swb, sb, logT, lcpT, out);
    } else {
        k_mono<<<B_ / 256, 256, 0, stream>>>(x, sw, sb, ll, tw, logT, out);
    }
}

// Round 12
// 206.953 us; speedup vs baseline: 2.2574x; 1.0124x over previous
//
#include <hip/hip_runtime.h>
#include <math.h>

#define B_  8192
#define F_  256
#define T_  32
#define NI_ 63
#define NL_ 64
#define C_  100
#define K2_ (T_*NL_)       // 2048 = GEMM2 K
#define NG  4              // y-slices (8 trees each) -> 512 blocks -> 2 blocks/CU
#define TPG 8              // trees per y-slice

typedef unsigned short u16;
typedef __attribute__((ext_vector_type(8))) short bf16x8;   // MFMA A/B frag
typedef __attribute__((ext_vector_type(4))) float f32x4;    // MFMA C/D frag

__device__ __forceinline__ u16 f2bf(float f) {
    unsigned int u = __float_as_uint(f);
    u += 0x7fffu + ((u >> 16) & 1u);      // RNE
    return (u16)(u >> 16);
}

// ws layout (bytes):  (inputs/outputs fp32 — established R5/R6/R10)
//   swb  : u16 [T_][NI_][F_] = 1,032,192
//   lcpT : u16 [112][K2_]    =   458,752
#define WSB_SWB  0
#define WSB_LCPT (T_*NI_*F_*2)
#define WSB_TOT  ((size_t)WSB_LCPT + 112*K2_*2)   // 1,490,944 B

// ---- prep: zero d_out + cvt sw->bf16 + weighted leaf-class-prob table ----
#define ZBLK   (B_*C_/256)        // 3200
#define SWBLK  (T_*NI_*F_/256)    // 2016
#define LCPBLK (T_*NL_/256)       // 8
__global__ void k_prep(const float* __restrict__ sw, const float* __restrict__ ll,
                       const float* __restrict__ tw, const float* __restrict__ logT,
                       u16* __restrict__ swb, u16* __restrict__ lcpT,
                       float* __restrict__ out) {
    int blk = blockIdx.x, tid = threadIdx.x;
    if (blk < ZBLK) {                       // zero output (atomic base)
        out[blk * 256 + tid] = 0.f;
        return;
    }
    blk -= ZBLK;
    if (blk < SWBLK) {                      // split_weights -> bf16
        int i = blk * 256 + tid;
        swb[i] = f2bf(sw[i]);
        return;
    }
    blk -= SWBLK;
    int idx = blk * 256 + tid;              // leaf row: t*64 + l, 0..2047
    int t = idx >> 6;
    float temp = __expf(logT[0]);
    temp = fminf(fmaxf(temp, 0.1f), 5.0f);
    float invt = 1.0f / temp;

    float m = -1e30f;
    for (int j = 0; j < T_; ++j) m = fmaxf(m, tw[j]);
    float s = 0.f;
    for (int j = 0; j < T_; ++j) s += __expf(tw[j] - m);
    float wt = __expf(tw[t] - m) / s;

    const float* row = ll + (size_t)idx * C_;
    float m2 = -1e30f;
    for (int c = 0; c < C_; ++c) m2 = fmaxf(m2, row[c]);
    float s2 = 0.f;
    for (int c = 0; c < C_; ++c) s2 += __expf((row[c] - m2) * invt);
    float sc = wt / s2;
    for (int c = 0; c < C_; ++c)
        lcpT[(size_t)c * K2_ + idx] = f2bf(sc * __expf((row[c] - m2) * invt));
    for (int c = C_; c < 112; ++c)
        lcpT[(size_t)c * K2_ + idx] = 0;    // pad rows feed discarded C-cols
}

// ---- fused: MFMA GEMM1 -> sigmoid -> subtree leaf walk -> MFMA GEMM2 ----
// grid (B_/64, NG), block 256; wave owns 16 b-rows; y-slice does TPG trees.
// NO __syncthreads: slog[w] is per-wave; within-wave LDS ordering via lgkmcnt.
// launch_bounds(256,1): VGPR cap 512 — R10/R11's 64-VGPR allocation serialized
// the 32 B-frag loads per tree (~29K stall-cycles/iter, the measured 96% idle).
__global__ __launch_bounds__(256, 1)
void k_fused(const float* __restrict__ x, const u16* __restrict__ swb,
             const float* __restrict__ sb, const float* __restrict__ logT,
             const u16* __restrict__ lcpT, float* __restrict__ out) {
    __shared__ float slog[4][16][68];
    int tid  = threadIdx.x;
    int w    = tid >> 6;
    int lane = tid & 63;
    int col  = lane & 15;
    int quad = lane >> 4;
    int mb   = blockIdx.x * 64 + w * 16;
    int tg   = blockIdx.y;

    float temp = __expf(logT[0]);
    temp = fminf(fmaxf(temp, 0.1f), 5.0f);
    float invt = 1.0f / temp;

    // A-frags packed in-register from fp32 x
    bf16x8 afr[8];
    #pragma unroll
    for (int ks = 0; ks < 8; ++ks) {
        const float4* px = (const float4*)(x + (size_t)(mb + col) * F_ + ks * 32 + quad * 8);
        float4 v0 = px[0], v1 = px[1];
        bf16x8 a;
        a[0] = (short)f2bf(v0.x); a[1] = (short)f2bf(v0.y);
        a[2] = (short)f2bf(v0.z); a[3] = (short)f2bf(v0.w);
        a[4] = (short)f2bf(v1.x); a[5] = (short)f2bf(v1.y);
        a[6] = (short)f2bf(v1.z); a[7] = (short)f2bf(v1.w);
        afr[ks] = a;
    }

    f32x4 accO[7];
    #pragma unroll
    for (int i = 0; i < 7; ++i) accO[i] = (f32x4){0.f, 0.f, 0.f, 0.f};

    #pragma unroll 1
    for (int ti = 0; ti < TPG; ++ti) {
        int t = tg * TPG + ti;

        // ---- GEMM1: logits[16 b][64 n] over K=256 (loads stay in flight now)
        f32x4 acc[4];
        #pragma unroll
        for (int i = 0; i < 4; ++i) acc[i] = (f32x4){0.f, 0.f, 0.f, 0.f};
        #pragma unroll
        for (int ks = 0; ks < 8; ++ks) {
            #pragma unroll
            for (int nt = 0; nt < 4; ++nt) {
                int n  = nt * 16 + col;
                int ne = n > 62 ? 62 : n;        // pad row; its column never read
                bf16x8 bfr = *(const bf16x8*)(swb + ((size_t)t * NI_ + ne) * F_
                                              + ks * 32 + quad * 8);
                acc[nt] = __builtin_amdgcn_mfma_f32_16x16x32_bf16(afr[ks], bfr, acc[nt], 0, 0, 0);
            }
        }

        // prior iteration's slog reads complete before overwrite (same wave)
        asm volatile("s_waitcnt lgkmcnt(0)" ::: "memory");
        // ---- C/D epilogue (R10-verified): bias+sigmoid -> slog[quad*4+r][n]
        #pragma unroll
        for (int nt = 0; nt < 4; ++nt) {
            int n = nt * 16 + col;
            float bias = (n < NI_) ? sb[t * NI_ + n] : 0.f;
            #pragma unroll
            for (int r = 0; r < 4; ++r) {
                float lg = (acc[nt][r] + bias) * invt;
                slog[w][quad * 4 + r][n] = 1.0f / (1.0f + __expf(-lg));
            }
        }
        // writes visible to this wave's cross-lane reads
        asm volatile("s_waitcnt lgkmcnt(0)" ::: "memory");

        // ---- leaf walk (R10-verified): lane builds its GEMM2 A-frag slots
        bf16x8 af0, af1;
        #pragma unroll
        for (int grp = 0; grp < 2; ++grp) {
            int s = (grp ? 11 : 7) + quad;
            float pref = 1.0f;
            int node = s;
            #pragma unroll
            for (int d = 0; d < 3; ++d) {
                int par = (node - 1) >> 1;
                float g = slog[w][col][par];
                pref = (node & 1) ? (pref - pref * g) : (pref * g);  // odd=left -> 1-g
                node = par;
            }
            float gs  = slog[w][col][s];
            float gl  = slog[w][col][2 * s + 1];
            float gr  = slog[w][col][2 * s + 2];
            float g00 = slog[w][col][4 * s + 3];
            float g01 = slog[w][col][4 * s + 4];
            float g10 = slog[w][col][4 * s + 5];
            float g11 = slog[w][col][4 * s + 6];
            #pragma unroll
            for (int j = 0; j < 8; ++j) {
                const int b2 = (j >> 2) & 1, b1 = (j >> 1) & 1, b0 = j & 1;
                float f3 = b2 ? gs : 1.0f - gs;
                float c1 = b2 ? gr : gl;
                float f4 = b1 ? c1 : 1.0f - c1;
                float c2 = b2 ? (b1 ? g11 : g10) : (b1 ? g01 : g00);
                float f5 = b0 ? c2 : 1.0f - c2;
                float p  = pref * f3 * f4 * f5;
                if (grp == 0) af0[j] = (short)f2bf(p);
                else          af1[j] = (short)f2bf(p);
            }
        }

        // ---- GEMM2: out[16 b][112 c] += leafprobs x lcpT (K=64 slice of tree t)
        #pragma unroll
        for (int nt = 0; nt < 7; ++nt) {
            int n = nt * 16 + col;
            const bf16x8 b0 = *(const bf16x8*)(lcpT + (size_t)n * K2_ + t * NL_ + quad * 8);
            const bf16x8 b1 = *(const bf16x8*)(lcpT + (size_t)n * K2_ + t * NL_ + 32 + quad * 8);
            accO[nt] = __builtin_amdgcn_mfma_f32_16x16x32_bf16(af0, b0, accO[nt], 0, 0, 0);
            accO[nt] = __builtin_amdgcn_mfma_f32_16x16x32_bf16(af1, b1, accO[nt], 0, 0, 0);
        }
    }

    // ---- fp32 atomics into d_out (zeroed by k_prep); NG contributors per cell
    #pragma unroll
    for (int nt = 0; nt < 7; ++nt) {
        int c = nt * 16 + col;
        if (c < C_) {
            #pragma unroll
            for (int r = 0; r < 4; ++r) {
                int b = mb + quad * 4 + r;
                atomicAdd(&out[(size_t)b * C_ + c], accO[nt][r]);
            }
        }
    }
}

// ---- guard path: zero fp32 output ----
__global__ void k_zf(float* __restrict__ out, int n) {
    int i = blockIdx.x * 256 + threadIdx.x;
    if (i < n) out[i] = 0.f;
}

// ---- zero-ws fallback (R5-verified structure, fp32 I/O) ----
__global__ void k_mono(const float* __restrict__ x, const float* __restrict__ sw,
                       const float* __restrict__ sb, const float* __restrict__ ll,
                       const float* __restrict__ tw, const float* __restrict__ logT,
                       float* __restrict__ outg) {
    __shared__ float slcp[NL_ * C_];
    int tid = threadIdx.x;
    int b = blockIdx.x * 256 + tid;

    float temp = __expf(logT[0]);
    temp = fminf(fmaxf(temp, 0.1f), 5.0f);
    float invt = 1.0f / temp;

    float m = -1e30f;
    for (int j = 0; j < T_; ++j) m = fmaxf(m, tw[j]);
    float sden = 0.f;
    for (int j = 0; j < T_; ++j) sden += __expf(tw[j] - m);

    float acc[C_];
    #pragma unroll
    for (int c = 0; c < C_; ++c) acc[c] = 0.f;

    for (int t = 0; t < T_; ++t) {
        __syncthreads();
        {
            int l = tid & 63, cq = tid >> 6;
            float wt = __expf(tw[t] - m) / sden;
            const float* row = ll + ((size_t)t * NL_ + l) * C_;
            float m2 = -1e30f;
            for (int c = 0; c < C_; ++c) m2 = fmaxf(m2, row[c]);
            float s2 = 0.f;
            for (int c = 0; c < C_; ++c) s2 += __expf((row[c] - m2) * invt);
            float sc = wt / s2;
            for (int c = cq * 25; c < cq * 25 + 25; ++c)
                slcp[l * C_ + c] = sc * __expf((row[c] - m2) * invt);
        }
        __syncthreads();

        float an[NI_];
        #pragma unroll
        for (int n = 0; n < NI_; ++n) an[n] = 0.f;
        for (int k = 0; k < F_; ++k) {
            float xv = x[(size_t)b * F_ + k];
            #pragma unroll
            for (int n = 0; n < NI_; ++n)
                an[n] = fmaf(xv, sw[((size_t)t * NI_ + n) * F_ + k], an[n]);
        }
        #pragma unroll
        for (int n = 0; n < NI_; ++n) {
            float lg = (an[n] + sb[t * NI_ + n]) * invt;
            an[n] = 1.0f / (1.0f + __expf(-lg));
        }
        #pragma unroll
        for (int l = 0; l < NL_; ++l) {
            int node = l + NI_;
            float p = 1.0f;
            #pragma unroll
            for (int d = 0; d < 6; ++d) {
                int par = (node - 1) >> 1;
                float gv = an[par];
                p = (node & 1) ? (p - p * gv) : (p * gv);
                node = par;
            }
            #pragma unroll
            for (int c = 0; c < C_; ++c)
                acc[c] = fmaf(p, slcp[l * C_ + c], acc[c]);
        }
    }
    for (int c = 0; c < C_; ++c)
        outg[(size_t)b * C_ + c] = acc[c];
}

extern "C" void kernel_launch(void* const* d_in, const int* in_sizes, int n_in,
                              void* d_out, int out_size, void* d_ws, size_t ws_size,
                              hipStream_t stream) {
    bool ok = (n_in >= 6)
           && (in_sizes[0] == B_ * F_)
           && (in_sizes[1] == T_ * NI_ * F_)
           && (in_sizes[2] == T_ * NI_)
           && (in_sizes[3] == T_ * NL_ * C_)
           && (in_sizes[4] == T_)
           && (in_sizes[5] == 1)
           && (out_size == B_ * C_);
    if (!ok) {
        k_zf<<<(out_size + 255) / 256, 256, 0, stream>>>((float*)d_out, out_size);
        return;
    }

    const float* x    = (const float*)d_in[0];
    const float* sw   = (const float*)d_in[1];
    const float* sb   = (const float*)d_in[2];
    const float* ll   = (const float*)d_in[3];
    const float* tw   = (const float*)d_in[4];
    const float* logT = (const float*)d_in[5];
    float* out = (float*)d_out;

    if (ws_size >= WSB_TOT) {
        u16* swb  = (u16*)((char*)d_ws + WSB_SWB);
        u16* lcpT = (u16*)((char*)d_ws + WSB_LCPT);

        k_prep <<<ZBLK + SWBLK + LCPBLK, 256, 0, stream>>>(sw, ll, tw, logT, swb, lcpT, out);
        k_fused<<<dim3(B_ / 64, NG), 256, 0, stream>>>(x, swb, sb, logT, lcpT, out);
    } else {
        k_mono<<<B_ / 256, 256, 0, stream>>>(x, sw, sb, ll, tw, logT, out);
    }
}

// Round 13
// 185.189 us; speedup vs baseline: 2.5227x; 1.1175x over previous
//
#include <hip/hip_runtime.h>
#include <math.h>

#define B_  8192
#define F_  256
#define T_  32
#define NI_ 63
#define NL_ 64
#define C_  100
#define K2_ (T_*NL_)       // 2048 = GEMM2 K
#define NG  4              // y-slices (8 trees each) -> 512 blocks
#define TPG 8              // trees per y-slice

typedef unsigned short u16;
typedef __attribute__((ext_vector_type(8))) short bf16x8;   // MFMA A/B frag
typedef __attribute__((ext_vector_type(4))) float f32x4;    // MFMA C/D frag

__device__ __forceinline__ u16 f2bf(float f) {
    unsigned int u = __float_as_uint(f);
    u += 0x7fffu + ((u >> 16) & 1u);      // RNE
    return (u16)(u >> 16);
}

// ws layout (bytes):  (inputs/outputs fp32 — established R5/R6/R10)
//   swb  : u16 [T_][NI_][F_] = 1,032,192
//   lcpT : u16 [112][K2_]    =   458,752
#define WSB_SWB  0
#define WSB_LCPT (T_*NI_*F_*2)
#define WSB_TOT  ((size_t)WSB_LCPT + 112*K2_*2)   // 1,490,944 B

// ---- prep: zero d_out + cvt sw->bf16 + weighted leaf-class-prob table ----
#define ZBLK   (B_*C_/256)        // 3200
#define SWBLK  (T_*NI_*F_/256)    // 2016
#define LCPBLK (T_*NL_/256)       // 8
__global__ void k_prep(const float* __restrict__ sw, const float* __restrict__ ll,
                       const float* __restrict__ tw, const float* __restrict__ logT,
                       u16* __restrict__ swb, u16* __restrict__ lcpT,
                       float* __restrict__ out) {
    int blk = blockIdx.x, tid = threadIdx.x;
    if (blk < ZBLK) {                       // zero output (atomic base)
        out[blk * 256 + tid] = 0.f;
        return;
    }
    blk -= ZBLK;
    if (blk < SWBLK) {                      // split_weights -> bf16
        int i = blk * 256 + tid;
        swb[i] = f2bf(sw[i]);
        return;
    }
    blk -= SWBLK;
    int idx = blk * 256 + tid;              // leaf row: t*64 + l, 0..2047
    int t = idx >> 6;
    float temp = __expf(logT[0]);
    temp = fminf(fmaxf(temp, 0.1f), 5.0f);
    float invt = 1.0f / temp;

    float m = -1e30f;
    for (int j = 0; j < T_; ++j) m = fmaxf(m, tw[j]);
    float s = 0.f;
    for (int j = 0; j < T_; ++j) s += __expf(tw[j] - m);
    float wt = __expf(tw[t] - m) / s;

    const float* row = ll + (size_t)idx * C_;
    float m2 = -1e30f;
    for (int c = 0; c < C_; ++c) m2 = fmaxf(m2, row[c]);
    float s2 = 0.f;
    for (int c = 0; c < C_; ++c) s2 += __expf((row[c] - m2) * invt);
    float sc = wt / s2;
    for (int c = 0; c < C_; ++c)
        lcpT[(size_t)c * K2_ + idx] = f2bf(sc * __expf((row[c] - m2) * invt));
    for (int c = C_; c < 112; ++c)
        lcpT[(size_t)c * K2_ + idx] = 0;    // pad rows feed discarded C-cols
}

// ---- fused: MFMA GEMM1 -> sigmoid -> subtree leaf walk -> MFMA GEMM2 ----
// grid (B_/64, NG), block 256; wave owns 16 b-rows; y-slice does TPG trees.
// R13: EXPLICIT load/compute separation. R10-R12's load->mfma->load->mfma
// source order compiled to 32 serialized round-trips/tree (68 VGPR, 96% stall).
__global__ __launch_bounds__(256, 1)
void k_fused(const float* __restrict__ x, const u16* __restrict__ swb,
             const float* __restrict__ sb, const float* __restrict__ logT,
             const u16* __restrict__ lcpT, float* __restrict__ out) {
    __shared__ float slog[4][16][68];
    int tid  = threadIdx.x;
    int w    = tid >> 6;
    int lane = tid & 63;
    int col  = lane & 15;
    int quad = lane >> 4;
    int mb   = blockIdx.x * 64 + w * 16;
    int tg   = blockIdx.y;

    float temp = __expf(logT[0]);
    temp = fminf(fmaxf(temp, 0.1f), 5.0f);
    float invt = 1.0f / temp;

    // A-frags packed in-register from fp32 x
    bf16x8 afr[8];
    #pragma unroll
    for (int ks = 0; ks < 8; ++ks) {
        const float4* px = (const float4*)(x + (size_t)(mb + col) * F_ + ks * 32 + quad * 8);
        float4 v0 = px[0], v1 = px[1];
        bf16x8 a;
        a[0] = (short)f2bf(v0.x); a[1] = (short)f2bf(v0.y);
        a[2] = (short)f2bf(v0.z); a[3] = (short)f2bf(v0.w);
        a[4] = (short)f2bf(v1.x); a[5] = (short)f2bf(v1.y);
        a[6] = (short)f2bf(v1.z); a[7] = (short)f2bf(v1.w);
        afr[ks] = a;
    }

    f32x4 accO[7];
    #pragma unroll
    for (int i = 0; i < 7; ++i) accO[i] = (f32x4){0.f, 0.f, 0.f, 0.f};

    #pragma unroll 1
    for (int ti = 0; ti < TPG; ++ti) {
        int t = tg * TPG + ti;

        // ---- GEMM1 stage 1: issue ALL 32 B-frag loads (one latency exposure)
        bf16x8 bfr[4][8];
        #pragma unroll
        for (int nt = 0; nt < 4; ++nt) {
            int n  = nt * 16 + col;
            int ne = n > 62 ? 62 : n;            // pad row; its column never read
            const u16* bp = swb + ((size_t)t * NI_ + ne) * F_ + quad * 8;
            #pragma unroll
            for (int ks = 0; ks < 8; ++ks)
                bfr[nt][ks] = *(const bf16x8*)(bp + ks * 32);
        }
        // ---- GEMM1 stage 2: 32 MFMAs, logits[16 b][64 n] over K=256
        f32x4 acc[4];
        #pragma unroll
        for (int i = 0; i < 4; ++i) acc[i] = (f32x4){0.f, 0.f, 0.f, 0.f};
        #pragma unroll
        for (int ks = 0; ks < 8; ++ks) {
            #pragma unroll
            for (int nt = 0; nt < 4; ++nt)
                acc[nt] = __builtin_amdgcn_mfma_f32_16x16x32_bf16(afr[ks], bfr[nt][ks], acc[nt], 0, 0, 0);
        }

        // ---- GEMM2 loads issued NOW: latency hidden behind epilogue+leaf walk
        bf16x8 lb0[7], lb1[7];
        #pragma unroll
        for (int nt = 0; nt < 7; ++nt) {
            int n = nt * 16 + col;
            lb0[nt] = *(const bf16x8*)(lcpT + (size_t)n * K2_ + t * NL_ + quad * 8);
            lb1[nt] = *(const bf16x8*)(lcpT + (size_t)n * K2_ + t * NL_ + 32 + quad * 8);
        }

        // prior iteration's slog reads complete before overwrite (same wave)
        asm volatile("s_waitcnt lgkmcnt(0)" ::: "memory");
        // ---- C/D epilogue (R10-verified): bias+sigmoid -> slog[quad*4+r][n]
        #pragma unroll
        for (int nt = 0; nt < 4; ++nt) {
            int n = nt * 16 + col;
            float bias = (n < NI_) ? sb[t * NI_ + n] : 0.f;
            #pragma unroll
            for (int r = 0; r < 4; ++r) {
                float lg = (acc[nt][r] + bias) * invt;
                slog[w][quad * 4 + r][n] = 1.0f / (1.0f + __expf(-lg));
            }
        }
        // writes visible to this wave's cross-lane reads
        asm volatile("s_waitcnt lgkmcnt(0)" ::: "memory");

        // ---- leaf walk (R10-verified): lane builds its GEMM2 A-frag slots
        bf16x8 af0, af1;
        #pragma unroll
        for (int grp = 0; grp < 2; ++grp) {
            int s = (grp ? 11 : 7) + quad;
            float pref = 1.0f;
            int node = s;
            #pragma unroll
            for (int d = 0; d < 3; ++d) {
                int par = (node - 1) >> 1;
                float g = slog[w][col][par];
                pref = (node & 1) ? (pref - pref * g) : (pref * g);  // odd=left -> 1-g
                node = par;
            }
            float gs  = slog[w][col][s];
            float gl  = slog[w][col][2 * s + 1];
            float gr  = slog[w][col][2 * s + 2];
            float g00 = slog[w][col][4 * s + 3];
            float g01 = slog[w][col][4 * s + 4];
            float g10 = slog[w][col][4 * s + 5];
            float g11 = slog[w][col][4 * s + 6];
            #pragma unroll
            for (int j = 0; j < 8; ++j) {
                const int b2 = (j >> 2) & 1, b1 = (j >> 1) & 1, b0 = j & 1;
                float f3 = b2 ? gs : 1.0f - gs;
                float c1 = b2 ? gr : gl;
                float f4 = b1 ? c1 : 1.0f - c1;
                float c2 = b2 ? (b1 ? g11 : g10) : (b1 ? g01 : g00);
                float f5 = b0 ? c2 : 1.0f - c2;
                float p  = pref * f3 * f4 * f5;
                if (grp == 0) af0[j] = (short)f2bf(p);
                else          af1[j] = (short)f2bf(p);
            }
        }

        // ---- GEMM2: out[16 b][112 c] += leafprobs x lcpT (K=64 slice of tree t)
        #pragma unroll
        for (int nt = 0; nt < 7; ++nt) {
            accO[nt] = __builtin_amdgcn_mfma_f32_16x16x32_bf16(af0, lb0[nt], accO[nt], 0, 0, 0);
            accO[nt] = __builtin_amdgcn_mfma_f32_16x16x32_bf16(af1, lb1[nt], accO[nt], 0, 0, 0);
        }
    }

    // ---- fp32 atomics into d_out (zeroed by k_prep); NG contributors per cell
    #pragma unroll
    for (int nt = 0; nt < 7; ++nt) {
        int c = nt * 16 + col;
        if (c < C_) {
            #pragma unroll
            for (int r = 0; r < 4; ++r) {
                int b = mb + quad * 4 + r;
                atomicAdd(&out[(size_t)b * C_ + c], accO[nt][r]);
            }
        }
    }
}

// ---- guard path: zero fp32 output ----
__global__ void k_zf(float* __restrict__ out, int n) {
    int i = blockIdx.x * 256 + threadIdx.x;
    if (i < n) out[i] = 0.f;
}

// ---- zero-ws fallback (R5-verified structure, fp32 I/O) ----
__global__ void k_mono(const float* __restrict__ x, const float* __restrict__ sw,
                       const float* __restrict__ sb, const float* __restrict__ ll,
                       const float* __restrict__ tw, const float* __restrict__ logT,
                       float* __restrict__ outg) {
    __shared__ float slcp[NL_ * C_];
    int tid = threadIdx.x;
    int b = blockIdx.x * 256 + tid;

    float temp = __expf(logT[0]);
    temp = fminf(fmaxf(temp, 0.1f), 5.0f);
    float invt = 1.0f / temp;

    float m = -1e30f;
    for (int j = 0; j < T_; ++j) m = fmaxf(m, tw[j]);
    float sden = 0.f;
    for (int j = 0; j < T_; ++j) sden += __expf(tw[j] - m);

    float acc[C_];
    #pragma unroll
    for (int c = 0; c < C_; ++c) acc[c] = 0.f;

    for (int t = 0; t < T_; ++t) {
        __syncthreads();
        {
            int l = tid & 63, cq = tid >> 6;
            float wt = __expf(tw[t] - m) / sden;
            const float* row = ll + ((size_t)t * NL_ + l) * C_;
            float m2 = -1e30f;
            for (int c = 0; c < C_; ++c) m2 = fmaxf(m2, row[c]);
            float s2 = 0.f;
            for (int c = 0; c < C_; ++c) s2 += __expf((row[c] - m2) * invt);
            float sc = wt / s2;
            for (int c = cq * 25; c < cq * 25 + 25; ++c)
                slcp[l * C_ + c] = sc * __expf((row[c] - m2) * invt);
        }
        __syncthreads();

        float an[NI_];
        #pragma unroll
        for (int n = 0; n < NI_; ++n) an[n] = 0.f;
        for (int k = 0; k < F_; ++k) {
            float xv = x[(size_t)b * F_ + k];
            #pragma unroll
            for (int n = 0; n < NI_; ++n)
                an[n] = fmaf(xv, sw[((size_t)t * NI_ + n) * F_ + k], an[n]);
        }
        #pragma unroll
        for (int n = 0; n < NI_; ++n) {
            float lg = (an[n] + sb[t * NI_ + n]) * invt;
            an[n] = 1.0f / (1.0f + __expf(-lg));
        }
        #pragma unroll
        for (int l = 0; l < NL_; ++l) {
            int node = l + NI_;
            float p = 1.0f;
            #pragma unroll
            for (int d = 0; d < 6; ++d) {
                int par = (node - 1) >> 1;
                float gv = an[par];
                p = (node & 1) ? (p - p * gv) : (p * gv);
                node = par;
            }
            #pragma unroll
            for (int c = 0; c < C_; ++c)
                acc[c] = fmaf(p, slcp[l * C_ + c], acc[c]);
        }
    }
    for (int c = 0; c < C_; ++c)
        outg[(size_t)b * C_ + c] = acc[c];
}

extern "C" void kernel_launch(void* const* d_in, const int* in_sizes, int n_in,
                              void* d_out, int out_size, void* d_ws, size_t ws_size,
                              hipStream_t stream) {
    bool ok = (n_in >= 6)
           && (in_sizes[0] == B_ * F_)
           && (in_sizes[1] == T_ * NI_ * F_)
           && (in_sizes[2] == T_ * NI_)
           && (in_sizes[3] == T_ * NL_ * C_)
           && (in_sizes[4] == T_)
           && (in_sizes[5] == 1)
           && (out_size == B_ * C_);
    if (!ok) {
        k_zf<<<(out_size + 255) / 256, 256, 0, stream>>>((float*)d_out, out_size);
        return;
    }

    const float* x    = (const float*)d_in[0];
    const float* sw   = (const float*)d_in[1];
    const float* sb   = (const float*)d_in[2];
    const float* ll   = (const float*)d_in[3];
    const float* tw   = (const float*)d_in[4];
    const float* logT = (const float*)d_in[5];
    float* out = (float*)d_out;

    if (ws_size >= WSB_TOT) {
        u16* swb  = (u16*)((char*)d_ws + WSB_SWB);
        u16* lcpT = (u16*)((char*)d_ws + WSB_LCPT);

        k_prep <<<ZBLK + SWBLK + LCPBLK, 256, 0, stream>>>(sw, ll, tw, logT, swb, lcpT, out);
        k_fused<<<dim3(B_ / 64, NG), 256, 0, stream>>>(x, swb, sb, logT, lcpT, out);
    } else {
        k_mono<<<B_ / 256, 256, 0, stream>>>(x, sw, sb, ll, tw, logT, out);
    }
}

// Round 14
// 159.563 us; speedup vs baseline: 2.9278x; 1.1606x over previous
//
#include <hip/hip_runtime.h>
#include <math.h>

#define B_  8192
#define F_  256
#define T_  32
#define NI_ 63
#define NL_ 64
#define C_  100
#define K2_ (T_*NL_)       // 2048 = GEMM2 K
#define NG  8              // y-slices -> 512 blocks (64 x 8)
#define TPG 4              // trees per y-slice

typedef unsigned short u16;
typedef __attribute__((ext_vector_type(8))) short bf16x8;   // MFMA A/B frag
typedef __attribute__((ext_vector_type(4))) float f32x4;    // MFMA C/D frag
typedef __attribute__((ext_vector_type(8))) unsigned short u16x8;

__device__ __forceinline__ u16 f2bf(float f) {
    unsigned int u = __float_as_uint(f);
    u += 0x7fffu + ((u >> 16) & 1u);      // RNE
    return (u16)(u >> 16);
}

// ws layout (bytes):
//   swb  : u16 [T_][NI_][F_] = 1,032,192
//   lcpT : u16 [112][K2_]    =   458,752
#define WSB_SWB  0
#define WSB_LCPT (T_*NI_*F_*2)
#define WSB_TOT  ((size_t)WSB_LCPT + 112*K2_*2)

// ---- prep: zero d_out + cvt sw->bf16 + weighted leaf-class-prob table ----
#define ZBLK   (B_*C_/256)        // 3200
#define SWBLK  (T_*NI_*F_/256)    // 2016
#define LCPBLK (T_*NL_/256)       // 8
__global__ void k_prep(const float* __restrict__ sw, const float* __restrict__ ll,
                       const float* __restrict__ tw, const float* __restrict__ logT,
                       u16* __restrict__ swb, u16* __restrict__ lcpT,
                       float* __restrict__ out) {
    int blk = blockIdx.x, tid = threadIdx.x;
    if (blk < ZBLK) { out[blk * 256 + tid] = 0.f; return; }
    blk -= ZBLK;
    if (blk < SWBLK) { int i = blk * 256 + tid; swb[i] = f2bf(sw[i]); return; }
    blk -= SWBLK;
    int idx = blk * 256 + tid;              // leaf row: t*64 + l
    int t = idx >> 6;
    float temp = __expf(logT[0]);
    temp = fminf(fmaxf(temp, 0.1f), 5.0f);
    float invt = 1.0f / temp;

    float m = -1e30f;
    for (int j = 0; j < T_; ++j) m = fmaxf(m, tw[j]);
    float s = 0.f;
    for (int j = 0; j < T_; ++j) s += __expf(tw[j] - m);
    float wt = __expf(tw[t] - m) / s;

    const float* row = ll + (size_t)idx * C_;
    float m2 = -1e30f;
    for (int c = 0; c < C_; ++c) m2 = fmaxf(m2, row[c]);
    float s2 = 0.f;
    for (int c = 0; c < C_; ++c) s2 += __expf((row[c] - m2) * invt);
    float sc = wt / s2;
    for (int c = 0; c < C_; ++c)
        lcpT[(size_t)c * K2_ + idx] = f2bf(sc * __expf((row[c] - m2) * invt));
    for (int c = C_; c < 112; ++c)
        lcpT[(size_t)c * K2_ + idx] = 0;
}

// ---- fused: LDS-staged tiles; MFMA GEMM1 -> sigmoid -> walk -> MFMA GEMM2 ----
// grid (B_/128, NG), block 256; wave owns 32 rows (2 m-tiles); TPG trees/block.
__global__ __launch_bounds__(256, 2)
void k_fused(const float* __restrict__ x, const u16* __restrict__ swb,
             const float* __restrict__ sb, const float* __restrict__ logT,
             const u16* __restrict__ lcpT, float* __restrict__ out) {
    __shared__ u16   swS[63 * 264];       // 63 rows x 528B (stride 264 elem): 33,264 B
    __shared__ u16   lcpS[8 * 112 * 8];   // [o=l/8][c][8]: frag-contiguous: 14,336 B
    __shared__ float slog[4][16][66];     // per-wave sigmoid tile: 16,896 B
    int tid  = threadIdx.x;
    int w    = tid >> 6;
    int lane = tid & 63;
    int col  = lane & 15;
    int quad = lane >> 4;
    int mb0  = blockIdx.x * 128 + w * 32; // wave's 32 batch rows
    int tg   = blockIdx.y;

    float temp = __expf(logT[0]);
    temp = fminf(fmaxf(temp, 0.1f), 5.0f);
    float invt = 1.0f / temp;

    // A-frags for both m-tiles, packed from fp32 x (one-time)
    bf16x8 afr[2][8];
    #pragma unroll
    for (int m = 0; m < 2; ++m) {
        #pragma unroll
        for (int ks = 0; ks < 8; ++ks) {
            const float4* px = (const float4*)(x + (size_t)(mb0 + m * 16 + col) * F_
                                               + ks * 32 + quad * 8);
            float4 v0 = px[0], v1 = px[1];
            bf16x8 a;
            a[0] = (short)f2bf(v0.x); a[1] = (short)f2bf(v0.y);
            a[2] = (short)f2bf(v0.z); a[3] = (short)f2bf(v0.w);
            a[4] = (short)f2bf(v1.x); a[5] = (short)f2bf(v1.y);
            a[6] = (short)f2bf(v1.z); a[7] = (short)f2bf(v1.w);
            afr[m][ks] = a;
        }
    }

    f32x4 accO[2][7];
    #pragma unroll
    for (int m = 0; m < 2; ++m)
        #pragma unroll
        for (int i = 0; i < 7; ++i) accO[m][i] = (f32x4){0.f, 0.f, 0.f, 0.f};

    #pragma unroll 1
    for (int ti = 0; ti < TPG; ++ti) {
        int t = tg * TPG + ti;

        // ---- cooperative staging: swb tile (63x512B -> stride 528B)
        {
            const char* gsrc = (const char*)(swb + (size_t)t * NI_ * F_);
            #pragma unroll
            for (int r = 0; r < 8; ++r) {
                int g = r * 4096 + tid * 16;         // byte offset in tile
                if (g < NI_ * F_ * 2) {              // 32256
                    int n   = g >> 9;
                    int k16 = (g & 511) >> 4;
                    u16x8 v = *(const u16x8*)(gsrc + g);
                    *(u16x8*)&swS[n * 264 + k16 * 8] = v;
                }
            }
            // lcpT tile: o = tid>>5 (leaf octet), c = r*32 + tid&31
            #pragma unroll
            for (int r = 0; r < 4; ++r) {
                int c = r * 32 + (tid & 31);
                int o = tid >> 5;
                if (c < 112) {
                    u16x8 v = *(const u16x8*)(lcpT + (size_t)c * K2_ + t * NL_ + o * 8);
                    *(u16x8*)&lcpS[(o * 112 + c) * 8] = v;
                }
            }
        }
        __syncthreads();

        // ---- GEMM1: logits[32 b][64 n] over K=256, B-frags from LDS (read 1x, use 2x)
        f32x4 acc[2][4];
        #pragma unroll
        for (int m = 0; m < 2; ++m)
            #pragma unroll
            for (int i = 0; i < 4; ++i) acc[m][i] = (f32x4){0.f, 0.f, 0.f, 0.f};
        #pragma unroll
        for (int ks = 0; ks < 8; ++ks) {
            #pragma unroll
            for (int nt = 0; nt < 4; ++nt) {
                int n  = nt * 16 + col;
                int ne = n > 62 ? 62 : n;            // pad col; its output never read
                bf16x8 bfr = *(const bf16x8*)&swS[ne * 264 + ks * 32 + quad * 8];
                acc[0][nt] = __builtin_amdgcn_mfma_f32_16x16x32_bf16(afr[0][ks], bfr, acc[0][nt], 0, 0, 0);
                acc[1][nt] = __builtin_amdgcn_mfma_f32_16x16x32_bf16(afr[1][ks], bfr, acc[1][nt], 0, 0, 0);
            }
        }

        // ---- per m-tile: epilogue -> leaf walk -> GEMM2 (slog reused, wave-serial)
        #pragma unroll
        for (int m = 0; m < 2; ++m) {
            asm volatile("s_waitcnt lgkmcnt(0)" ::: "memory");  // prior slog readers done
            #pragma unroll
            for (int nt = 0; nt < 4; ++nt) {
                int n = nt * 16 + col;
                float bias = (n < NI_) ? sb[t * NI_ + n] : 0.f;
                #pragma unroll
                for (int r = 0; r < 4; ++r) {
                    float lg = (acc[m][nt][r] + bias) * invt;
                    slog[w][quad * 4 + r][n] = 1.0f / (1.0f + __expf(-lg));
                }
            }
            asm volatile("s_waitcnt lgkmcnt(0)" ::: "memory");  // writes visible in-wave

            bf16x8 af0, af1;
            #pragma unroll
            for (int grp = 0; grp < 2; ++grp) {
                int s = (grp ? 11 : 7) + quad;
                float pref = 1.0f;
                int node = s;
                #pragma unroll
                for (int d = 0; d < 3; ++d) {
                    int par = (node - 1) >> 1;
                    float g = slog[w][col][par];
                    pref = (node & 1) ? (pref - pref * g) : (pref * g);  // odd=left -> 1-g
                    node = par;
                }
                float gs  = slog[w][col][s];
                float gl  = slog[w][col][2 * s + 1];
                float gr  = slog[w][col][2 * s + 2];
                float g00 = slog[w][col][4 * s + 3];
                float g01 = slog[w][col][4 * s + 4];
                float g10 = slog[w][col][4 * s + 5];
                float g11 = slog[w][col][4 * s + 6];
                #pragma unroll
                for (int j = 0; j < 8; ++j) {
                    const int b2 = (j >> 2) & 1, b1 = (j >> 1) & 1, b0 = j & 1;
                    float f3 = b2 ? gs : 1.0f - gs;
                    float c1 = b2 ? gr : gl;
                    float f4 = b1 ? c1 : 1.0f - c1;
                    float c2 = b2 ? (b1 ? g11 : g10) : (b1 ? g01 : g00);
                    float f5 = b0 ? c2 : 1.0f - c2;
                    float p  = pref * f3 * f4 * f5;
                    if (grp == 0) af0[j] = (short)f2bf(p);
                    else          af1[j] = (short)f2bf(p);
                }
            }

            #pragma unroll
            for (int nt = 0; nt < 7; ++nt) {
                int n = nt * 16 + col;
                bf16x8 lb0 = *(const bf16x8*)&lcpS[(quad * 112 + n) * 8];        // leaves 0..31
                bf16x8 lb1 = *(const bf16x8*)&lcpS[((4 + quad) * 112 + n) * 8];  // leaves 32..63
                accO[m][nt] = __builtin_amdgcn_mfma_f32_16x16x32_bf16(af0, lb0, accO[m][nt], 0, 0, 0);
                accO[m][nt] = __builtin_amdgcn_mfma_f32_16x16x32_bf16(af1, lb1, accO[m][nt], 0, 0, 0);
            }
        }
        __syncthreads();   // all waves done reading tiles before next staging
    }

    // ---- fp32 atomics into d_out (zeroed by k_prep); NG contributors per cell
    #pragma unroll
    for (int m = 0; m < 2; ++m) {
        #pragma unroll
        for (int nt = 0; nt < 7; ++nt) {
            int c = nt * 16 + col;
            if (c < C_) {
                #pragma unroll
                for (int r = 0; r < 4; ++r) {
                    int b = mb0 + m * 16 + quad * 4 + r;
                    atomicAdd(&out[(size_t)b * C_ + c], accO[m][nt][r]);
                }
            }
        }
    }
}

// ---- guard path: zero fp32 output ----
__global__ void k_zf(float* __restrict__ out, int n) {
    int i = blockIdx.x * 256 + threadIdx.x;
    if (i < n) out[i] = 0.f;
}

// ---- zero-ws fallback (R5-verified structure, fp32 I/O) ----
__global__ void k_mono(const float* __restrict__ x, const float* __restrict__ sw,
                       const float* __restrict__ sb, const float* __restrict__ ll,
                       const float* __restrict__ tw, const float* __restrict__ logT,
                       float* __restrict__ outg) {
    __shared__ float slcp[NL_ * C_];
    int tid = threadIdx.x;
    int b = blockIdx.x * 256 + tid;

    float temp = __expf(logT[0]);
    temp = fminf(fmaxf(temp, 0.1f), 5.0f);
    float invt = 1.0f / temp;

    float m = -1e30f;
    for (int j = 0; j < T_; ++j) m = fmaxf(m, tw[j]);
    float sden = 0.f;
    for (int j = 0; j < T_; ++j) sden += __expf(tw[j] - m);

    float acc[C_];
    #pragma unroll
    for (int c = 0; c < C_; ++c) acc[c] = 0.f;

    for (int t = 0; t < T_; ++t) {
        __syncthreads();
        {
            int l = tid & 63, cq = tid >> 6;
            float wt = __expf(tw[t] - m) / sden;
            const float* row = ll + ((size_t)t * NL_ + l) * C_;
            float m2 = -1e30f;
            for (int c = 0; c < C_; ++c) m2 = fmaxf(m2, row[c]);
            float s2 = 0.f;
            for (int c = 0; c < C_; ++c) s2 += __expf((row[c] - m2) * invt);
            float sc = wt / s2;
            for (int c = cq * 25; c < cq * 25 + 25; ++c)
                slcp[l * C_ + c] = sc * __expf((row[c] - m2) * invt);
        }
        __syncthreads();

        float an[NI_];
        #pragma unroll
        for (int n = 0; n < NI_; ++n) an[n] = 0.f;
        for (int k = 0; k < F_; ++k) {
            float xv = x[(size_t)b * F_ + k];
            #pragma unroll
            for (int n = 0; n < NI_; ++n)
                an[n] = fmaf(xv, sw[((size_t)t * NI_ + n) * F_ + k], an[n]);
        }
        #pragma unroll
        for (int n = 0; n < NI_; ++n) {
            float lg = (an[n] + sb[t * NI_ + n]) * invt;
            an[n] = 1.0f / (1.0f + __expf(-lg));
        }
        #pragma unroll
        for (int l = 0; l < NL_; ++l) {
            int node = l + NI_;
            float p = 1.0f;
            #pragma unroll
            for (int d = 0; d < 6; ++d) {
                int par = (node - 1) >> 1;
                float gv = an[par];
                p = (node & 1) ? (p - p * gv) : (p * gv);
                node = par;
            }
            #pragma unroll
            for (int c = 0; c < C_; ++c)
                acc[c] = fmaf(p, slcp[l * C_ + c], acc[c]);
        }
    }
    for (int c = 0; c < C_; ++c)
        outg[(size_t)b * C_ + c] = acc[c];
}

extern "C" void kernel_launch(void* const* d_in, const int* in_sizes, int n_in,
                              void* d_out, int out_size, void* d_ws, size_t ws_size,
                              hipStream_t stream) {
    bool ok = (n_in >= 6)
           && (in_sizes[0] == B_ * F_)
           && (in_sizes[1] == T_ * NI_ * F_)
           && (in_sizes[2] == T_ * NI_)
           && (in_sizes[3] == T_ * NL_ * C_)
           && (in_sizes[4] == T_)
           && (in_sizes[5] == 1)
           && (out_size == B_ * C_);
    if (!ok) {
        k_zf<<<(out_size + 255) / 256, 256, 0, stream>>>((float*)d_out, out_size);
        return;
    }

    const float* x    = (const float*)d_in[0];
    const float* sw   = (const float*)d_in[1];
    const float* sb   = (const float*)d_in[2];
    const float* ll   = (const float*)d_in[3];
    const float* tw   = (const float*)d_in[4];
    const float* logT = (const float*)d_in[5];
    float* out = (float*)d_out;

    if (ws_size >= WSB_TOT) {
        u16* swb  = (u16*)((char*)d_ws + WSB_SWB);
        u16* lcpT = (u16*)((char*)d_ws + WSB_LCPT);

        k_prep <<<ZBLK + SWBLK + LCPBLK, 256, 0, stream>>>(sw, ll, tw, logT, swb, lcpT, out);
        k_fused<<<dim3(B_ / 128, NG), 256, 0, stream>>>(x, swb, sb, logT, lcpT, out);
    } else {
        k_mono<<<B_ / 256, 256, 0, stream>>>(x, sw, sb, ll, tw, logT, out);
    }
}